// Round 8
// baseline (2414.088 us; speedup 1.0000x reference)
//
#include <hip/hip_runtime.h>
#include <hip/hip_bf16.h>

#define TT 12
#define HDIM 128
#define ODIM 12
#define KS0 136        // LDS h-row stride in shorts (272 B; 0 bank conflicts measured R4)
#define TPAD 36        // fp32 GCN gemm LDS pad

typedef short bf16x8 __attribute__((ext_vector_type(8)));
typedef float f32x16 __attribute__((ext_vector_type(16)));
typedef _Float16 h16x4 __attribute__((ext_vector_type(4)));

__device__ __forceinline__ float fastrcp(float x) { return __builtin_amdgcn_rcpf(x); }
__device__ __forceinline__ float sigf(float x) { return fastrcp(1.f + __expf(-x)); }
__device__ __forceinline__ float tanh_fast(float x) { return 1.f - 2.f * fastrcp(1.f + __expf(2.f * x)); }
__device__ __forceinline__ unsigned short f2bf(float f) {
    union { float f; unsigned int u; } v; v.f = f;
    unsigned int r = v.u + 0x7FFFu + ((v.u >> 16) & 1u);
    return (unsigned short)(r >> 16);
}

// ---------------- weight pre-pack into MFMA B-fragment order ----------------
// K=128 for all 3 matrices. slot = (mat*16 + cb)*8 + s  (384 slots x 1 KB = 384 KB)
// element = Wpk[(slot*64 + lane)*8 + j];  B[k][col]: col=cb*32+(lane&31), k=s*16+(lane>>5)*8+j
__global__ void pack_kernel(const float* __restrict__ Whh0, const float* __restrict__ Wih1,
                            const float* __restrict__ Whh1, unsigned short* __restrict__ Wpk)
{
    int idx = blockIdx.x * 256 + threadIdx.x;
    if (idx >= 384 * 64) return;
    int lane = idx & 63;
    int slot = idx >> 6;
    int mat = slot >> 7;
    int rem = slot & 127;
    int cb = rem >> 3, s = rem & 7;
    int col = cb * 32 + (lane & 31);
    const float* src = (mat == 0) ? Whh0 : (mat == 1) ? Wih1 : Whh1;
#pragma unroll
    for (int j = 0; j < 8; ++j) {
        int k = s * 16 + ((lane >> 5) << 3) + j;
        Wpk[((size_t)(slot * 64 + lane) << 3) + j] = f2bf(src[col * 128 + k]);
    }
}

// ---------------- L0: layer-0 LSTM, Whh0 resident in LDS (unchanged from R7) ----------------
__global__ __launch_bounds__(512, 1) void lstm_l0_kernel(
    const float* __restrict__ x,              // [N][12][2]
    const unsigned short* __restrict__ Wpk,   // mat0 = Whh0 packed (128 KB)
    const float* __restrict__ Wih0,           // [512][2]
    const float* __restrict__ bih0, const float* __restrict__ bhh0,
    unsigned short* __restrict__ h0seq,       // [N][12][128] bf16 out
    int N, int ntiles)
{
    __shared__ unsigned short wlds[65536];    // 128 KB
    __shared__ unsigned short hA0[64 * KS0];  // 17.4 KB
    __shared__ float xls[64 * 24];            // 6 KB

    const int tid  = threadIdx.x;
    const int w    = tid >> 6;
    const int ln   = tid & 63;
    const int ln31 = ln & 31;
    const int half = ln >> 5;
    const int wsub = w & 3;
    const int rb   = w >> 2;
    const int col  = wsub * 32 + ln31;

    for (int i = tid * 8; i < 65536; i += 512 * 8)
        *(bf16x8*)(wlds + i) = *(const bf16x8*)(Wpk + i);

    float wx0[4], wx1[4], br0[4];
#pragma unroll
    for (int g = 0; g < 4; ++g) {
        int row = (g << 7) + col;
        wx0[g] = Wih0[row * 2 + 0];
        wx1[g] = Wih0[row * 2 + 1];
        br0[g] = bih0[row] + bhh0[row];
    }

    for (int tile = blockIdx.x; tile < ntiles; tile += gridDim.x) {
        const int nbase = tile * 64;
        __syncthreads();
        for (int i = tid; i < 64 * 24; i += 512) {
            int n = nbase + i / 24;
            xls[i] = (n < N) ? x[nbase * 24 + i] : 0.f;
        }
        for (int i = tid; i < 64 * KS0; i += 512) hA0[i] = 0;
        float c0[16];
#pragma unroll
        for (int r = 0; r < 16; ++r) c0[r] = 0.f;
        __syncthreads();

        for (int t = 0; t < TT; ++t) {
            f32x16 acc[4];
#pragma unroll
            for (int g = 0; g < 4; ++g)
#pragma unroll
                for (int e = 0; e < 16; ++e) acc[g][e] = 0.f;
#pragma unroll
            for (int s = 0; s < 8; ++s) {
                bf16x8 a = *(const bf16x8*)(hA0 + (rb * 32 + ln31) * KS0 + s * 16 + half * 8);
#pragma unroll
                for (int g = 0; g < 4; ++g) {
                    int cb = g * 4 + wsub;
                    bf16x8 b = *(const bf16x8*)(wlds + (((cb * 8 + s) * 64 + ln) << 3));
                    acc[g] = __builtin_amdgcn_mfma_f32_32x32x16_bf16(a, b, acc[g], 0, 0, 0);
                }
            }
            __syncthreads();                   // B1: hA0 reads done
#pragma unroll
            for (int r = 0; r < 16; ++r) {
                int node = rb * 32 + (r & 3) + 8 * (r >> 2) + 4 * half;
                float xa = xls[node * 24 + t * 2 + 0];
                float xb = xls[node * 24 + t * 2 + 1];
                float zi = acc[0][r] + br0[0] + wx0[0] * xa + wx1[0] * xb;
                float zf = acc[1][r] + br0[1] + wx0[1] * xa + wx1[1] * xb;
                float zg = acc[2][r] + br0[2] + wx0[2] * xa + wx1[2] * xb;
                float zo = acc[3][r] + br0[3] + wx0[3] * xa + wx1[3] * xb;
                float cn = sigf(zf) * c0[r] + sigf(zi) * tanh_fast(zg);
                c0[r] = cn;
                float h = sigf(zo) * tanh_fast(cn);
                unsigned short us = f2bf(h);
                hA0[node * KS0 + col] = us;
                int n = nbase + node;
                if (n < N) h0seq[(n * TT + t) * HDIM + col] = us;
            }
            __syncthreads();                   // B2: h0_t visible
        }
    }
}

// ---------------- A: z1in = h0seq @ Wih1^T + b1  (Wih1 LDS-resident, persistent) ----------------
// z1in layout: [row][ch 0..127][gate 0..3] fp16 -> 8 B vectors on both ends.
__global__ __launch_bounds__(512, 1) void zin_gemm_kernel(
    const unsigned short* __restrict__ h0,    // h0seq + n0*12*128 (bf16 rows)
    const unsigned short* __restrict__ Wpk,   // +65536 = Wih1 packed
    const float* __restrict__ bih1, const float* __restrict__ bhh1,
    _Float16* __restrict__ z1in,              // [nrows][512]
    int nrows)
{
    __shared__ unsigned short wlds[65536];    // 128 KB

    const int tid  = threadIdx.x;
    const int w    = tid >> 6;
    const int ln   = tid & 63;
    const int ln31 = ln & 31;
    const int half = ln >> 5;
    const int wsub = w & 3;
    const int rb   = w >> 2;                  // row half of the 64-row tile
    const int ch   = wsub * 32 + ln31;

    for (int i = tid * 8; i < 65536; i += 512 * 8)
        *(bf16x8*)(wlds + i) = *(const bf16x8*)(Wpk + 65536 + i);

    float br1[4];
#pragma unroll
    for (int g = 0; g < 4; ++g) {
        int row = (g << 7) + ch;
        br1[g] = bih1[row] + bhh1[row];
    }
    __syncthreads();

    const bf16x8 zv = {0, 0, 0, 0, 0, 0, 0, 0};
    const int ntile = (nrows + 63) >> 6;
    for (int tile = blockIdx.x; tile < ntile; tile += gridDim.x) {
        const int r0 = tile * 64;
        f32x16 acc[4];
#pragma unroll
        for (int g = 0; g < 4; ++g)
#pragma unroll
            for (int e = 0; e < 16; ++e) acc[g][e] = 0.f;

        const int arow = r0 + rb * 32 + ln31;
        const bool aok = arow < nrows;
#pragma unroll
        for (int s = 0; s < 8; ++s) {
            bf16x8 a = aok
                ? __builtin_nontemporal_load((const bf16x8*)(h0 + (size_t)arow * HDIM + s * 16 + half * 8))
                : zv;
#pragma unroll
            for (int g = 0; g < 4; ++g) {
                int cb = g * 4 + wsub;
                bf16x8 b = *(const bf16x8*)(wlds + (((cb * 8 + s) * 64 + ln) << 3));
                acc[g] = __builtin_amdgcn_mfma_f32_32x32x16_bf16(a, b, acc[g], 0, 0, 0);
            }
        }
#pragma unroll
        for (int r = 0; r < 16; ++r) {
            int rr = rb * 32 + (r & 3) + 8 * (r >> 2) + 4 * half;
            int row = r0 + rr;
            if (row < nrows) {
                h16x4 v;
#pragma unroll
                for (int g = 0; g < 4; ++g) v[g] = (_Float16)(acc[g][r] + br1[g]);
                *(h16x4*)(z1in + (size_t)row * 512 + ch * 4) = v;
            }
        }
    }
}

// ---------------- B: layer-1 recurrence, Whh1 LDS-resident, persistent ----------------
__global__ __launch_bounds__(512, 1) void lstm_l1b_kernel(
    const _Float16* __restrict__ z1in,        // [(n1-n0)*12][512] (ch-gate order)
    const unsigned short* __restrict__ Wpk,   // +131072 = Whh1 packed
    float* __restrict__ hbuf,                 // [N][128] fp32 out
    int n0, int n1)
{
    __shared__ unsigned short wlds[65536];    // 128 KB
    __shared__ unsigned short hA1[64 * KS0];  // 17.4 KB

    const int tid  = threadIdx.x;
    const int w    = tid >> 6;
    const int ln   = tid & 63;
    const int ln31 = ln & 31;
    const int half = ln >> 5;
    const int wsub = w & 3;
    const int rb   = w >> 2;
    const int ch   = wsub * 32 + ln31;

    for (int i = tid * 8; i < 65536; i += 512 * 8)
        *(bf16x8*)(wlds + i) = *(const bf16x8*)(Wpk + 131072 + i);

    const int nodes = n1 - n0;
    const int ntile = (nodes + 63) >> 6;
    const h16x4 z0v = {(_Float16)0.f, (_Float16)0.f, (_Float16)0.f, (_Float16)0.f};

    for (int tile = blockIdx.x; tile < ntile; tile += gridDim.x) {
        __syncthreads();
        for (int i = tid; i < 64 * KS0; i += 512) hA1[i] = 0;
        float c1[16];
#pragma unroll
        for (int r = 0; r < 16; ++r) c1[r] = 0.f;
        __syncthreads();

        for (int t = 0; t < TT; ++t) {
            f32x16 acc[4];
#pragma unroll
            for (int g = 0; g < 4; ++g)
#pragma unroll
                for (int e = 0; e < 16; ++e) acc[g][e] = 0.f;
#pragma unroll
            for (int s = 0; s < 8; ++s) {
                bf16x8 a = *(const bf16x8*)(hA1 + (rb * 32 + ln31) * KS0 + s * 16 + half * 8);
#pragma unroll
                for (int g = 0; g < 4; ++g) {
                    int cb = g * 4 + wsub;
                    bf16x8 b = *(const bf16x8*)(wlds + (((cb * 8 + s) * 64 + ln) << 3));
                    acc[g] = __builtin_amdgcn_mfma_f32_32x32x16_bf16(a, b, acc[g], 0, 0, 0);
                }
            }
            __syncthreads();                   // B1: hA1 reads done
#pragma unroll
            for (int r = 0; r < 16; ++r) {
                int rr = rb * 32 + (r & 3) + 8 * (r >> 2) + 4 * half;
                int nloc = tile * 64 + rr;
                h16x4 z4 = (nloc < nodes)
                    ? __builtin_nontemporal_load((const h16x4*)(z1in + ((size_t)nloc * TT + t) * 512 + ch * 4))
                    : z0v;
                float zi = acc[0][r] + (float)z4[0];
                float zf = acc[1][r] + (float)z4[1];
                float zg = acc[2][r] + (float)z4[2];
                float zo = acc[3][r] + (float)z4[3];
                float cn = sigf(zf) * c1[r] + sigf(zi) * tanh_fast(zg);
                c1[r] = cn;
                float h = sigf(zo) * tanh_fast(cn);
                if (t + 1 < TT) {
                    hA1[rr * KS0 + ch] = f2bf(h);
                } else {
                    int n = n0 + nloc;
                    if (n < n1) hbuf[n * HDIM + ch] = h;
                }
            }
            __syncthreads();                   // B2: h1_t visible
        }
    }
}

// ---------------- GCN (unchanged) ----------------
__global__ void deg_count_kernel(const int* __restrict__ ei, int* __restrict__ degi, int E)
{
    int e = blockIdx.x * 256 + threadIdx.x;
    if (e < E) atomicAdd(&degi[ei[E + e]], 1);
}

__global__ void row_alloc_kernel(const int* __restrict__ degi, int* __restrict__ row_ptr,
                                 float* __restrict__ dinv, int* __restrict__ counter, int N)
{
    int n = blockIdx.x * 256 + threadIdx.x;
    int lane = threadIdx.x & 63;
    int v = (n < N) ? degi[n] : 0;
    int incl = v;
    for (int off = 1; off < 64; off <<= 1) {
        int u = __shfl_up(incl, off);
        if (lane >= off) incl += u;
    }
    int base = 0;
    if (lane == 63) base = atomicAdd(counter, incl);
    base = __shfl(base, 63);
    if (n < N) {
        row_ptr[n] = base + (incl - v);
        dinv[n] = rsqrtf((float)(v + 1));
    }
}

__global__ void csr_fill_kernel(const int* __restrict__ ei, const int* __restrict__ row_ptr,
                                int* __restrict__ fill, int* __restrict__ csr_src, int E)
{
    int e = blockIdx.x * 256 + threadIdx.x;
    if (e < E) {
        int d = ei[E + e];
        int p = atomicAdd(&fill[d], 1);
        csr_src[row_ptr[d] + p] = ei[e];
    }
}

__global__ __launch_bounds__(256) void gemm128_kernel(const float* __restrict__ X,
                                                      const float* __restrict__ W,
                                                      float* __restrict__ Y, int N)
{
    __shared__ float XT[128 * TPAD];
    const int tid = threadIdx.x;
    const int nbase = blockIdx.x * 32;
    for (int idx = tid; idx < 32 * 128; idx += 256) {
        int m = idx >> 7, k = idx & 127;
        int n = nbase + m;
        XT[k * TPAD + m] = (n < N) ? X[n * HDIM + k] : 0.f;
    }
    __syncthreads();
    const int c  = tid & 63;
    const int mb = (tid >> 6) << 3;
    float acc[8][2];
#pragma unroll
    for (int i = 0; i < 8; ++i) { acc[i][0] = 0.f; acc[i][1] = 0.f; }
    for (int k = 0; k < 128; ++k) {
        const float* xr = &XT[k * TPAD + mb];
        float4 a0 = *(const float4*)(xr);
        float4 a1 = *(const float4*)(xr + 4);
        float a[8] = {a0.x, a0.y, a0.z, a0.w, a1.x, a1.y, a1.z, a1.w};
        float b0 = W[k * HDIM + c];
        float b1 = W[k * HDIM + c + 64];
#pragma unroll
        for (int i = 0; i < 8; ++i) {
            acc[i][0] = fmaf(a[i], b0, acc[i][0]);
            acc[i][1] = fmaf(a[i], b1, acc[i][1]);
        }
    }
#pragma unroll
    for (int i = 0; i < 8; ++i) {
        int n = nbase + mb + i;
        if (n < N) {
            Y[n * HDIM + c]      = acc[i][0];
            Y[n * HDIM + c + 64] = acc[i][1];
        }
    }
}

__global__ void gemm12_kernel(const float* __restrict__ X, const float* __restrict__ W2,
                              float* __restrict__ Y, int N)
{
    int idx = blockIdx.x * 256 + threadIdx.x;
    int n = idx / ODIM, c = idx - n * ODIM;
    if (n >= N) return;
    float acc = 0.f;
    for (int k = 0; k < 128; ++k) acc = fmaf(X[n * HDIM + k], W2[k * ODIM + c], acc);
    Y[n * ODIM + c] = acc;
}

__global__ __launch_bounds__(128) void agg128_kernel(const float* __restrict__ hW,
        const int* __restrict__ row_ptr, const int* __restrict__ degi,
        const int* __restrict__ csr_src, const float* __restrict__ dinv,
        const float* __restrict__ bias, float* __restrict__ out, int N, int do_relu)
{
    int n = blockIdx.x;
    int c = threadIdx.x;
    float dn = dinv[n];
    float acc = hW[n * HDIM + c] * dn * dn;
    int start = row_ptr[n];
    int cnt = degi[n];
    for (int i = 0; i < cnt; ++i) {
        int s = csr_src[start + i];
        acc = fmaf(hW[s * HDIM + c], dinv[s] * dn, acc);
    }
    float v = acc + bias[c];
    if (do_relu) v = fmaxf(v, 0.f);
    out[n * HDIM + c] = v;
}

__global__ void agg12_kernel(const float* __restrict__ hW, const int* __restrict__ row_ptr,
        const int* __restrict__ degi, const int* __restrict__ csr_src,
        const float* __restrict__ dinv, const float* __restrict__ b2,
        float* __restrict__ out, int N)
{
    int idx = blockIdx.x * 256 + threadIdx.x;
    int n = idx / ODIM, c = idx - n * ODIM;
    if (n >= N) return;
    float dn = dinv[n];
    float acc = hW[n * ODIM + c] * dn * dn;
    int start = row_ptr[n], cnt = degi[n];
    for (int i = 0; i < cnt; ++i) {
        int s = csr_src[start + i];
        acc = fmaf(hW[s * ODIM + c], dinv[s] * dn, acc);
    }
    out[n * ODIM + c] = acc + b2[c];
}

extern "C" void kernel_launch(void* const* d_in, const int* in_sizes, int n_in,
                              void* d_out, int out_size, void* d_ws, size_t ws_size,
                              hipStream_t stream)
{
    const float* x     = (const float*)d_in[0];
    const int*   ei    = (const int*)d_in[1];
    const float* Wih0  = (const float*)d_in[2];
    const float* Whh0  = (const float*)d_in[3];
    const float* bih0  = (const float*)d_in[4];
    const float* bhh0  = (const float*)d_in[5];
    const float* Wih1  = (const float*)d_in[6];
    const float* Whh1  = (const float*)d_in[7];
    const float* bih1  = (const float*)d_in[8];
    const float* bhh1  = (const float*)d_in[9];
    const float* W0    = (const float*)d_in[10];
    const float* b0    = (const float*)d_in[11];
    const float* W1    = (const float*)d_in[12];
    const float* b1    = (const float*)d_in[13];
    const float* W2    = (const float*)d_in[14];
    const float* b2    = (const float*)d_in[15];
    float* out = (float*)d_out;

    const int N = in_sizes[0] / (TT * 2);
    const int E = in_sizes[1] / 2;

    // ---- workspace layout ----
    unsigned short* Wpk = (unsigned short*)d_ws;          // 384 KB
    float* fbase = (float*)((char*)d_ws + 393216);
    float* hbuf = fbase;                                  // N*128 fp32
    float* buf1 = hbuf + (size_t)N * HDIM;                // N*128
    float* buf2 = buf1 + (size_t)N * HDIM;                // N*128
    float* dinv = buf2 + (size_t)N * HDIM;                // N
    int* degi    = (int*)(dinv + N);                      // N
    int* fill    = degi + N;                              // N
    int* counter = fill + N;                              // 1
    int* row_ptr = counter + 1;                           // N
    int* csr_src = row_ptr + N;                           // E
    size_t h0_off = (((size_t)((char*)(csr_src + E) - (char*)d_ws)) + 255) & ~(size_t)255;
    unsigned short* h0seq = (unsigned short*)((char*)d_ws + h0_off);   // N*12*128 bf16 (153.6 MB)
    size_t z_off = (h0_off + (size_t)N * TT * HDIM * 2 + 255) & ~(size_t)255;

    // adaptive z1in placement
    const size_t per_node = (size_t)TT * 512 * 2;         // 12288 B/node
    long long tail = (ws_size > z_off) ? (long long)(ws_size - z_off) : 0;
    _Float16* z1in;
    int chunk;
    if (tail >= (long long)N * (long long)per_node) {
        z1in = (_Float16*)((char*)d_ws + z_off);  chunk = N;
    } else if (tail >= (long long)8192 * (long long)per_node) {
        z1in = (_Float16*)((char*)d_ws + z_off);  chunk = (int)(tail / per_node) & ~63;
    } else {
        z1in = (_Float16*)buf1;  chunk = 4096;    // 50.3 MB in buf1+buf2 (dead during LSTM)
    }

    hipMemsetAsync(degi, 0, (size_t)(2 * N + 1) * sizeof(int), stream);

    pack_kernel<<<(384 * 64 + 255) / 256, 256, 0, stream>>>(Whh0, Wih1, Whh1, Wpk);

    const int ntiles = (N + 63) / 64;
    lstm_l0_kernel<<<256, 512, 0, stream>>>(x, Wpk, Wih0, bih0, bhh0, h0seq, N, ntiles);

    for (int n0 = 0; n0 < N; n0 += chunk) {
        int n1 = (n0 + chunk < N) ? n0 + chunk : N;
        int nrows = (n1 - n0) * TT;
        int ga = (nrows + 63) / 64; if (ga > 256) ga = 256;
        int gb = ((n1 - n0) + 63) / 64; if (gb > 256) gb = 256;
        zin_gemm_kernel<<<ga, 512, 0, stream>>>(
            h0seq + (size_t)n0 * TT * HDIM, Wpk, bih1, bhh1, z1in, nrows);
        lstm_l1b_kernel<<<gb, 512, 0, stream>>>(z1in, Wpk, hbuf, n0, n1);
    }

    deg_count_kernel<<<(E + 255) / 256, 256, 0, stream>>>(ei, degi, E);
    row_alloc_kernel<<<(N + 255) / 256, 256, 0, stream>>>(degi, row_ptr, dinv, counter, N);
    csr_fill_kernel<<<(E + 255) / 256, 256, 0, stream>>>(ei, row_ptr, fill, csr_src, E);

    gemm128_kernel<<<(N + 31) / 32, 256, 0, stream>>>(hbuf, W0, buf1, N);
    agg128_kernel<<<N, 128, 0, stream>>>(buf1, row_ptr, degi, csr_src, dinv, b0, buf2, N, 1);
    gemm128_kernel<<<(N + 31) / 32, 256, 0, stream>>>(buf2, W1, buf1, N);
    agg128_kernel<<<N, 128, 0, stream>>>(buf1, row_ptr, degi, csr_src, dinv, b1, buf2, N, 1);
    gemm12_kernel<<<((size_t)N * ODIM + 255) / 256, 256, 0, stream>>>(buf2, W2, buf1, N);
    agg12_kernel<<<((size_t)N * ODIM + 255) / 256, 256, 0, stream>>>(
        buf1, row_ptr, degi, csr_src, dinv, b2, out, N);
}

// Round 9
// 1133.543 us; speedup vs baseline: 2.1297x; 2.1297x over previous
//
#include <hip/hip_runtime.h>
#include <hip/hip_bf16.h>

#define TT 12
#define HDIM 128
#define ODIM 12
#define KS0 136        // LDS h-row stride in shorts (272 B; 0 bank conflicts measured R4/R7)
#define TPAD 36        // fp32 GCN gemm LDS pad

typedef short bf16x8 __attribute__((ext_vector_type(8)));
typedef float f32x16 __attribute__((ext_vector_type(16)));

__device__ __forceinline__ float fastrcp(float x) { return __builtin_amdgcn_rcpf(x); }
__device__ __forceinline__ float sigf(float x) { return fastrcp(1.f + __expf(-x)); }
__device__ __forceinline__ float tanh_fast(float x) { return 1.f - 2.f * fastrcp(1.f + __expf(2.f * x)); }
__device__ __forceinline__ unsigned short f2bf(float f) {
    union { float f; unsigned int u; } v; v.f = f;
    unsigned int r = v.u + 0x7FFFu + ((v.u >> 16) & 1u);
    return (unsigned short)(r >> 16);
}

// ---------------- weight pre-pack into MFMA B-fragment order ----------------
// K=128 for all 3 matrices. slot = (mat*16 + cb)*8 + s  (384 slots x 1 KB = 384 KB)
// element = Wpk[(slot*64 + lane)*8 + j];  B[k][col]: col=cb*32+(lane&31), k=s*16+(lane>>5)*8+j
__global__ void pack_kernel(const float* __restrict__ Whh0, const float* __restrict__ Wih1,
                            const float* __restrict__ Whh1, unsigned short* __restrict__ Wpk)
{
    int idx = blockIdx.x * 256 + threadIdx.x;
    if (idx >= 384 * 64) return;
    int lane = idx & 63;
    int slot = idx >> 6;
    int mat = slot >> 7;
    int rem = slot & 127;
    int cb = rem >> 3, s = rem & 7;
    int col = cb * 32 + (lane & 31);
    const float* src = (mat == 0) ? Whh0 : (mat == 1) ? Wih1 : Whh1;
#pragma unroll
    for (int j = 0; j < 8; ++j) {
        int k = s * 16 + ((lane >> 5) << 3) + j;
        Wpk[((size_t)(slot * 64 + lane) << 3) + j] = f2bf(src[col * 128 + k]);
    }
}

// ---------------- L0: layer-0 LSTM, Whh0 resident in LDS (unchanged; 264 us) ----------------
__global__ __launch_bounds__(512, 1) void lstm_l0_kernel(
    const float* __restrict__ x,              // [N][12][2]
    const unsigned short* __restrict__ Wpk,   // mat0 = Whh0 packed (128 KB)
    const float* __restrict__ Wih0,           // [512][2]
    const float* __restrict__ bih0, const float* __restrict__ bhh0,
    unsigned short* __restrict__ h0seq,       // [N][12][128] bf16 out
    int N, int ntiles)
{
    __shared__ unsigned short wlds[65536];    // 128 KB
    __shared__ unsigned short hA0[64 * KS0];  // 17.4 KB
    __shared__ float xls[64 * 24];            // 6 KB

    const int tid  = threadIdx.x;
    const int w    = tid >> 6;
    const int ln   = tid & 63;
    const int ln31 = ln & 31;
    const int half = ln >> 5;
    const int wsub = w & 3;
    const int rb   = w >> 2;
    const int col  = wsub * 32 + ln31;

    for (int i = tid * 8; i < 65536; i += 512 * 8)
        *(bf16x8*)(wlds + i) = *(const bf16x8*)(Wpk + i);

    float wx0[4], wx1[4], br0[4];
#pragma unroll
    for (int g = 0; g < 4; ++g) {
        int row = (g << 7) + col;
        wx0[g] = Wih0[row * 2 + 0];
        wx1[g] = Wih0[row * 2 + 1];
        br0[g] = bih0[row] + bhh0[row];
    }

    for (int tile = blockIdx.x; tile < ntiles; tile += gridDim.x) {
        const int nbase = tile * 64;
        __syncthreads();
        for (int i = tid; i < 64 * 24; i += 512) {
            int n = nbase + i / 24;
            xls[i] = (n < N) ? x[nbase * 24 + i] : 0.f;
        }
        for (int i = tid; i < 64 * KS0; i += 512) hA0[i] = 0;
        float c0[16];
#pragma unroll
        for (int r = 0; r < 16; ++r) c0[r] = 0.f;
        __syncthreads();

        for (int t = 0; t < TT; ++t) {
            f32x16 acc[4];
#pragma unroll
            for (int g = 0; g < 4; ++g)
#pragma unroll
                for (int e = 0; e < 16; ++e) acc[g][e] = 0.f;
#pragma unroll
            for (int s = 0; s < 8; ++s) {
                bf16x8 a = *(const bf16x8*)(hA0 + (rb * 32 + ln31) * KS0 + s * 16 + half * 8);
#pragma unroll
                for (int g = 0; g < 4; ++g) {
                    int cb = g * 4 + wsub;
                    bf16x8 b = *(const bf16x8*)(wlds + (((cb * 8 + s) * 64 + ln) << 3));
                    acc[g] = __builtin_amdgcn_mfma_f32_32x32x16_bf16(a, b, acc[g], 0, 0, 0);
                }
            }
            __syncthreads();                   // B1: hA0 reads done
#pragma unroll
            for (int r = 0; r < 16; ++r) {
                int node = rb * 32 + (r & 3) + 8 * (r >> 2) + 4 * half;
                float xa = xls[node * 24 + t * 2 + 0];
                float xb = xls[node * 24 + t * 2 + 1];
                float zi = acc[0][r] + br0[0] + wx0[0] * xa + wx1[0] * xb;
                float zf = acc[1][r] + br0[1] + wx0[1] * xa + wx1[1] * xb;
                float zg = acc[2][r] + br0[2] + wx0[2] * xa + wx1[2] * xb;
                float zo = acc[3][r] + br0[3] + wx0[3] * xa + wx1[3] * xb;
                float cn = sigf(zf) * c0[r] + sigf(zi) * tanh_fast(zg);
                c0[r] = cn;
                float h = sigf(zo) * tanh_fast(cn);
                unsigned short us = f2bf(h);
                hA0[node * KS0 + col] = us;
                int n = nbase + node;
                if (n < N) h0seq[(n * TT + t) * HDIM + col] = us;
            }
            __syncthreads();                   // B2: h0_t visible
        }
    }
}

// ---------------- L1 fused: Whh1 in LDS, Wih1 fragments in REGISTERS ----------------
// 256 thr = 4 waves (1/SIMD -> 512-reg budget). Wave w owns cb = {w, 4+w, 8+w, 12+w}.
// M=64 nodes/tile (2 row-blocks of 32). Zero weight restream; h0seq read once (nt).
__global__ __launch_bounds__(256, 1) void lstm_l1f_kernel(
    const unsigned short* __restrict__ h0seq, // [N][12][128] bf16
    const unsigned short* __restrict__ Wpk,   // +65536 = Wih1, +131072 = Whh1
    const float* __restrict__ bih1, const float* __restrict__ bhh1,
    float* __restrict__ hbuf,                 // [N][128] fp32 out
    int N, int ntiles)
{
    __shared__ unsigned short wlds[65536];    // Whh1, 128 KB
    __shared__ unsigned short hA1[64 * KS0];  // 17.4 KB

    const int tid  = threadIdx.x;
    const int w    = tid >> 6;                // 0..3 = channel group
    const int ln   = tid & 63;
    const int ln31 = ln & 31;
    const int half = ln >> 5;
    const int ch   = w * 32 + ln31;           // output channel 0..127

    // Whh1 -> LDS (coalesced b128)
    for (int i = tid * 8; i < 65536; i += 256 * 8)
        *(bf16x8*)(wlds + i) = *(const bf16x8*)(Wpk + 131072 + i);

    // Wih1 fragments -> registers (one-time, 128 VGPRs)
    bf16x8 wfr[4][8];
#pragma unroll
    for (int g = 0; g < 4; ++g)
#pragma unroll
        for (int s = 0; s < 8; ++s) {
            int cb = g * 4 + w;
            wfr[g][s] = *(const bf16x8*)(Wpk + 65536 + (((cb * 8 + s) * 64 + ln) << 3));
        }

    float br1[4];
#pragma unroll
    for (int g = 0; g < 4; ++g) {
        int row = (g << 7) + ch;
        br1[g] = bih1[row] + bhh1[row];
    }

    const bf16x8 zv = {0, 0, 0, 0, 0, 0, 0, 0};
    __syncthreads();                           // wlds ready

    for (int tile = blockIdx.x; tile < ntiles; tile += gridDim.x) {
        __syncthreads();                       // prev tile's hA1 reads done
        for (int i = tid; i < 64 * KS0; i += 256) hA1[i] = 0;
        float c1[2][16];
#pragma unroll
        for (int rb = 0; rb < 2; ++rb)
#pragma unroll
            for (int r = 0; r < 16; ++r) c1[rb][r] = 0.f;
        __syncthreads();

        const int na0 = tile * 64 + ln31;      // A-row for rb=0
        const int na1 = na0 + 32;              // A-row for rb=1
        const bool ok0 = na0 < N, ok1 = na1 < N;

        for (int t = 0; t < TT; ++t) {
            // issue h0 A-loads early (streamed once -> nt)
            bf16x8 a0[2][8];
#pragma unroll
            for (int s = 0; s < 8; ++s) {
                a0[0][s] = ok0 ? __builtin_nontemporal_load(
                    (const bf16x8*)(h0seq + ((size_t)na0 * TT + t) * HDIM + s * 16 + half * 8)) : zv;
                a0[1][s] = ok1 ? __builtin_nontemporal_load(
                    (const bf16x8*)(h0seq + ((size_t)na1 * TT + t) * HDIM + s * 16 + half * 8)) : zv;
            }

            f32x16 acc[2][4];
#pragma unroll
            for (int rb = 0; rb < 2; ++rb)
#pragma unroll
                for (int g = 0; g < 4; ++g)
#pragma unroll
                    for (int e = 0; e < 16; ++e) acc[rb][g][e] = 0.f;

            // recurrent gemm (LDS A, LDS B) — overlaps the in-flight a0 loads
#pragma unroll
            for (int s = 0; s < 8; ++s) {
                bf16x8 a1[2];
#pragma unroll
                for (int rb = 0; rb < 2; ++rb)
                    a1[rb] = *(const bf16x8*)(hA1 + (rb * 32 + ln31) * KS0 + s * 16 + half * 8);
#pragma unroll
                for (int g = 0; g < 4; ++g) {
                    int cb = g * 4 + w;
                    bf16x8 b = *(const bf16x8*)(wlds + (((cb * 8 + s) * 64 + ln) << 3));
#pragma unroll
                    for (int rb = 0; rb < 2; ++rb)
                        acc[rb][g] = __builtin_amdgcn_mfma_f32_32x32x16_bf16(a1[rb], b, acc[rb][g], 0, 0, 0);
                }
            }
            // input gemm (register A, register B)
#pragma unroll
            for (int s = 0; s < 8; ++s)
#pragma unroll
                for (int g = 0; g < 4; ++g)
#pragma unroll
                    for (int rb = 0; rb < 2; ++rb)
                        acc[rb][g] = __builtin_amdgcn_mfma_f32_32x32x16_bf16(a0[rb][s], wfr[g][s], acc[rb][g], 0, 0, 0);
            __syncthreads();                   // B1: hA1 reads done

#pragma unroll
            for (int rb = 0; rb < 2; ++rb) {
#pragma unroll
                for (int r = 0; r < 16; ++r) {
                    int rr = rb * 32 + (r & 3) + 8 * (r >> 2) + 4 * half;
                    float zi = acc[rb][0][r] + br1[0];
                    float zf = acc[rb][1][r] + br1[1];
                    float zg = acc[rb][2][r] + br1[2];
                    float zo = acc[rb][3][r] + br1[3];
                    float cn = sigf(zf) * c1[rb][r] + sigf(zi) * tanh_fast(zg);
                    c1[rb][r] = cn;
                    float h = sigf(zo) * tanh_fast(cn);
                    if (t + 1 < TT) {
                        hA1[rr * KS0 + ch] = f2bf(h);
                    } else {
                        int n = tile * 64 + rr;
                        if (n < N) hbuf[n * HDIM + ch] = h;
                    }
                }
            }
            __syncthreads();                   // B2: h1_t visible
        }
    }
}

// ---------------- GCN (unchanged this round) ----------------
__global__ void deg_count_kernel(const int* __restrict__ ei, int* __restrict__ degi, int E)
{
    int e = blockIdx.x * 256 + threadIdx.x;
    if (e < E) atomicAdd(&degi[ei[E + e]], 1);
}

__global__ void row_alloc_kernel(const int* __restrict__ degi, int* __restrict__ row_ptr,
                                 float* __restrict__ dinv, int* __restrict__ counter, int N)
{
    int n = blockIdx.x * 256 + threadIdx.x;
    int lane = threadIdx.x & 63;
    int v = (n < N) ? degi[n] : 0;
    int incl = v;
    for (int off = 1; off < 64; off <<= 1) {
        int u = __shfl_up(incl, off);
        if (lane >= off) incl += u;
    }
    int base = 0;
    if (lane == 63) base = atomicAdd(counter, incl);
    base = __shfl(base, 63);
    if (n < N) {
        row_ptr[n] = base + (incl - v);
        dinv[n] = rsqrtf((float)(v + 1));
    }
}

__global__ void csr_fill_kernel(const int* __restrict__ ei, const int* __restrict__ row_ptr,
                                int* __restrict__ fill, int* __restrict__ csr_src, int E)
{
    int e = blockIdx.x * 256 + threadIdx.x;
    if (e < E) {
        int d = ei[E + e];
        int p = atomicAdd(&fill[d], 1);
        csr_src[row_ptr[d] + p] = ei[e];
    }
}

__global__ __launch_bounds__(256) void gemm128_kernel(const float* __restrict__ X,
                                                      const float* __restrict__ W,
                                                      float* __restrict__ Y, int N)
{
    __shared__ float XT[128 * TPAD];
    const int tid = threadIdx.x;
    const int nbase = blockIdx.x * 32;
    for (int idx = tid; idx < 32 * 128; idx += 256) {
        int m = idx >> 7, k = idx & 127;
        int n = nbase + m;
        XT[k * TPAD + m] = (n < N) ? X[n * HDIM + k] : 0.f;
    }
    __syncthreads();
    const int c  = tid & 63;
    const int mb = (tid >> 6) << 3;
    float acc[8][2];
#pragma unroll
    for (int i = 0; i < 8; ++i) { acc[i][0] = 0.f; acc[i][1] = 0.f; }
    for (int k = 0; k < 128; ++k) {
        const float* xr = &XT[k * TPAD + mb];
        float4 a0 = *(const float4*)(xr);
        float4 a1 = *(const float4*)(xr + 4);
        float a[8] = {a0.x, a0.y, a0.z, a0.w, a1.x, a1.y, a1.z, a1.w};
        float b0 = W[k * HDIM + c];
        float b1 = W[k * HDIM + c + 64];
#pragma unroll
        for (int i = 0; i < 8; ++i) {
            acc[i][0] = fmaf(a[i], b0, acc[i][0]);
            acc[i][1] = fmaf(a[i], b1, acc[i][1]);
        }
    }
#pragma unroll
    for (int i = 0; i < 8; ++i) {
        int n = nbase + mb + i;
        if (n < N) {
            Y[n * HDIM + c]      = acc[i][0];
            Y[n * HDIM + c + 64] = acc[i][1];
        }
    }
}

__global__ void gemm12_kernel(const float* __restrict__ X, const float* __restrict__ W2,
                              float* __restrict__ Y, int N)
{
    int idx = blockIdx.x * 256 + threadIdx.x;
    int n = idx / ODIM, c = idx - n * ODIM;
    if (n >= N) return;
    float acc = 0.f;
    for (int k = 0; k < 128; ++k) acc = fmaf(X[n * HDIM + k], W2[k * ODIM + c], acc);
    Y[n * ODIM + c] = acc;
}

__global__ __launch_bounds__(128) void agg128_kernel(const float* __restrict__ hW,
        const int* __restrict__ row_ptr, const int* __restrict__ degi,
        const int* __restrict__ csr_src, const float* __restrict__ dinv,
        const float* __restrict__ bias, float* __restrict__ out, int N, int do_relu)
{
    int n = blockIdx.x;
    int c = threadIdx.x;
    float dn = dinv[n];
    float acc = hW[n * HDIM + c] * dn * dn;
    int start = row_ptr[n];
    int cnt = degi[n];
    for (int i = 0; i < cnt; ++i) {
        int s = csr_src[start + i];
        acc = fmaf(hW[s * HDIM + c], dinv[s] * dn, acc);
    }
    float v = acc + bias[c];
    if (do_relu) v = fmaxf(v, 0.f);
    out[n * HDIM + c] = v;
}

__global__ void agg12_kernel(const float* __restrict__ hW, const int* __restrict__ row_ptr,
        const int* __restrict__ degi, const int* __restrict__ csr_src,
        const float* __restrict__ dinv, const float* __restrict__ b2,
        float* __restrict__ out, int N)
{
    int idx = blockIdx.x * 256 + threadIdx.x;
    int n = idx / ODIM, c = idx - n * ODIM;
    if (n >= N) return;
    float dn = dinv[n];
    float acc = hW[n * ODIM + c] * dn * dn;
    int start = row_ptr[n], cnt = degi[n];
    for (int i = 0; i < cnt; ++i) {
        int s = csr_src[start + i];
        acc = fmaf(hW[s * ODIM + c], dinv[s] * dn, acc);
    }
    out[n * ODIM + c] = acc + b2[c];
}

extern "C" void kernel_launch(void* const* d_in, const int* in_sizes, int n_in,
                              void* d_out, int out_size, void* d_ws, size_t ws_size,
                              hipStream_t stream)
{
    const float* x     = (const float*)d_in[0];
    const int*   ei    = (const int*)d_in[1];
    const float* Wih0  = (const float*)d_in[2];
    const float* Whh0  = (const float*)d_in[3];
    const float* bih0  = (const float*)d_in[4];
    const float* bhh0  = (const float*)d_in[5];
    const float* Wih1  = (const float*)d_in[6];
    const float* Whh1  = (const float*)d_in[7];
    const float* bih1  = (const float*)d_in[8];
    const float* bhh1  = (const float*)d_in[9];
    const float* W0    = (const float*)d_in[10];
    const float* b0    = (const float*)d_in[11];
    const float* W1    = (const float*)d_in[12];
    const float* b1    = (const float*)d_in[13];
    const float* W2    = (const float*)d_in[14];
    const float* b2    = (const float*)d_in[15];
    float* out = (float*)d_out;

    const int N = in_sizes[0] / (TT * 2);
    const int E = in_sizes[1] / 2;

    // ---- workspace layout ----
    unsigned short* Wpk = (unsigned short*)d_ws;          // 384 KB
    float* fbase = (float*)((char*)d_ws + 393216);
    float* hbuf = fbase;                                  // N*128 fp32
    float* buf1 = hbuf + (size_t)N * HDIM;                // N*128
    float* buf2 = buf1 + (size_t)N * HDIM;                // N*128
    float* dinv = buf2 + (size_t)N * HDIM;                // N
    int* degi    = (int*)(dinv + N);                      // N
    int* fill    = degi + N;                              // N
    int* counter = fill + N;                              // 1
    int* row_ptr = counter + 1;                           // N
    int* csr_src = row_ptr + N;                           // E
    size_t h0_off = (((size_t)((char*)(csr_src + E) - (char*)d_ws)) + 255) & ~(size_t)255;
    unsigned short* h0seq = (unsigned short*)((char*)d_ws + h0_off);   // N*12*128 bf16 (153.6 MB)

    hipMemsetAsync(degi, 0, (size_t)(2 * N + 1) * sizeof(int), stream);

    pack_kernel<<<(384 * 64 + 255) / 256, 256, 0, stream>>>(Whh0, Wih1, Whh1, Wpk);

    const int ntiles = (N + 63) / 64;
    lstm_l0_kernel<<<256, 512, 0, stream>>>(x, Wpk, Wih0, bih0, bhh0, h0seq, N, ntiles);
    lstm_l1f_kernel<<<256, 256, 0, stream>>>(h0seq, Wpk, bih1, bhh1, hbuf, N, ntiles);

    deg_count_kernel<<<(E + 255) / 256, 256, 0, stream>>>(ei, degi, E);
    row_alloc_kernel<<<(N + 255) / 256, 256, 0, stream>>>(degi, row_ptr, dinv, counter, N);
    csr_fill_kernel<<<(E + 255) / 256, 256, 0, stream>>>(ei, row_ptr, fill, csr_src, E);

    gemm128_kernel<<<(N + 31) / 32, 256, 0, stream>>>(hbuf, W0, buf1, N);
    agg128_kernel<<<N, 128, 0, stream>>>(buf1, row_ptr, degi, csr_src, dinv, b0, buf2, N, 1);
    gemm128_kernel<<<(N + 31) / 32, 256, 0, stream>>>(buf2, W1, buf1, N);
    agg128_kernel<<<N, 128, 0, stream>>>(buf1, row_ptr, degi, csr_src, dinv, b1, buf2, N, 1);
    gemm12_kernel<<<((size_t)N * ODIM + 255) / 256, 256, 0, stream>>>(buf2, W2, buf1, N);
    agg12_kernel<<<((size_t)N * ODIM + 255) / 256, 256, 0, stream>>>(
        buf1, row_ptr, degi, csr_src, dinv, b2, out, N);
}

// Round 10
// 1068.210 us; speedup vs baseline: 2.2599x; 1.0612x over previous
//
#include <hip/hip_runtime.h>
#include <hip/hip_bf16.h>

#define TT 12
#define HDIM 128
#define ODIM 12
#define KS0 136        // LDS h-row stride in shorts (272 B)
#define TPAD 36        // fp32 GCN gemm LDS pad

typedef short bf16x8 __attribute__((ext_vector_type(8)));
typedef float f32x16 __attribute__((ext_vector_type(16)));
typedef float f32x4  __attribute__((ext_vector_type(4)));

__device__ __forceinline__ float fastrcp(float x) { return __builtin_amdgcn_rcpf(x); }
__device__ __forceinline__ float sigf(float x) { return fastrcp(1.f + __expf(-x)); }
__device__ __forceinline__ float tanh_fast(float x) { return 1.f - 2.f * fastrcp(1.f + __expf(2.f * x)); }
__device__ __forceinline__ unsigned short f2bf(float f) {
    union { float f; unsigned int u; } v; v.f = f;
    unsigned int r = v.u + 0x7FFFu + ((v.u >> 16) & 1u);
    return (unsigned short)(r >> 16);
}

// ---------------- weight pre-pack ----------------
// mat0 (Whh0): 32x32-frag layout, slots 0..127 at offset 0 (for l0)
//   col = cb*32+(lane&31), k = s*16+(lane>>5)*8+j, slot = cb*8+s
// mat1 (Wih1) at +65536, mat2 (Whh1) at +131072: 16x16-frag layout
//   col = ct*16+(lane&15), k = ks*32+(lane>>4)*8+j, slot = ct*4+ks  (ct 0..31, ks 0..3)
__global__ void pack_kernel(const float* __restrict__ Whh0, const float* __restrict__ Wih1,
                            const float* __restrict__ Whh1, unsigned short* __restrict__ Wpk)
{
    int idx = blockIdx.x * 256 + threadIdx.x;
    if (idx >= 384 * 64) return;
    int lane = idx & 63;
    int slot = idx >> 6;
    int mat = slot >> 7;
    int rem = slot & 127;
    if (mat == 0) {
        int cb = rem >> 3, s = rem & 7;
        int col = cb * 32 + (lane & 31);
#pragma unroll
        for (int j = 0; j < 8; ++j) {
            int k = s * 16 + ((lane >> 5) << 3) + j;
            Wpk[((size_t)(slot * 64 + lane) << 3) + j] = f2bf(Whh0[col * 128 + k]);
        }
    } else {
        const float* src = (mat == 1) ? Wih1 : Whh1;
        int ct = rem >> 2, ks = rem & 3;
        int col = ct * 16 + (lane & 15);
#pragma unroll
        for (int j = 0; j < 8; ++j) {
            int k = ks * 32 + ((lane >> 4) << 3) + j;
            Wpk[((size_t)(slot * 64 + lane) << 3) + j] = f2bf(src[col * 128 + k]);
        }
    }
}

// ---------------- L0: layer-0 LSTM, Whh0 resident in LDS (unchanged; ~264 us) ----------------
__global__ __launch_bounds__(512, 1) void lstm_l0_kernel(
    const float* __restrict__ x,
    const unsigned short* __restrict__ Wpk,
    const float* __restrict__ Wih0,
    const float* __restrict__ bih0, const float* __restrict__ bhh0,
    unsigned short* __restrict__ h0seq,       // [N][12][128] bf16
    int N, int ntiles)
{
    __shared__ unsigned short wlds[65536];
    __shared__ unsigned short hA0[64 * KS0];
    __shared__ float xls[64 * 24];

    const int tid  = threadIdx.x;
    const int w    = tid >> 6;
    const int ln   = tid & 63;
    const int ln31 = ln & 31;
    const int half = ln >> 5;
    const int wsub = w & 3;
    const int rb   = w >> 2;
    const int col  = wsub * 32 + ln31;

    for (int i = tid * 8; i < 65536; i += 512 * 8)
        *(bf16x8*)(wlds + i) = *(const bf16x8*)(Wpk + i);

    float wx0[4], wx1[4], br0[4];
#pragma unroll
    for (int g = 0; g < 4; ++g) {
        int row = (g << 7) + col;
        wx0[g] = Wih0[row * 2 + 0];
        wx1[g] = Wih0[row * 2 + 1];
        br0[g] = bih0[row] + bhh0[row];
    }

    for (int tile = blockIdx.x; tile < ntiles; tile += gridDim.x) {
        const int nbase = tile * 64;
        __syncthreads();
        for (int i = tid; i < 64 * 24; i += 512) {
            int n = nbase + i / 24;
            xls[i] = (n < N) ? x[nbase * 24 + i] : 0.f;
        }
        for (int i = tid; i < 64 * KS0; i += 512) hA0[i] = 0;
        float c0[16];
#pragma unroll
        for (int r = 0; r < 16; ++r) c0[r] = 0.f;
        __syncthreads();

        for (int t = 0; t < TT; ++t) {
            f32x16 acc[4];
#pragma unroll
            for (int g = 0; g < 4; ++g)
#pragma unroll
                for (int e = 0; e < 16; ++e) acc[g][e] = 0.f;
#pragma unroll
            for (int s = 0; s < 8; ++s) {
                bf16x8 a = *(const bf16x8*)(hA0 + (rb * 32 + ln31) * KS0 + s * 16 + half * 8);
#pragma unroll
                for (int g = 0; g < 4; ++g) {
                    int cb = g * 4 + wsub;
                    bf16x8 b = *(const bf16x8*)(wlds + (((cb * 8 + s) * 64 + ln) << 3));
                    acc[g] = __builtin_amdgcn_mfma_f32_32x32x16_bf16(a, b, acc[g], 0, 0, 0);
                }
            }
            __syncthreads();                   // B1
#pragma unroll
            for (int r = 0; r < 16; ++r) {
                int node = rb * 32 + (r & 3) + 8 * (r >> 2) + 4 * half;
                float xa = xls[node * 24 + t * 2 + 0];
                float xb = xls[node * 24 + t * 2 + 1];
                float zi = acc[0][r] + br0[0] + wx0[0] * xa + wx1[0] * xb;
                float zf = acc[1][r] + br0[1] + wx0[1] * xa + wx1[1] * xb;
                float zg = acc[2][r] + br0[2] + wx0[2] * xa + wx1[2] * xb;
                float zo = acc[3][r] + br0[3] + wx0[3] * xa + wx1[3] * xb;
                float cn = sigf(zf) * c0[r] + sigf(zi) * tanh_fast(zg);
                c0[r] = cn;
                float h = sigf(zo) * tanh_fast(cn);
                unsigned short us = f2bf(h);
                hA0[node * KS0 + col] = us;
                int n = nbase + node;
                if (n < N) h0seq[(n * TT + t) * HDIM + col] = us;
            }
            __syncthreads();                   // B2
        }
    }
}

// ---------------- L1: 16x16x32 MFMA, 8 waves (2/SIMD), Whh1 LDS + Wih1 regs ----------------
// Wave w owns ch block [w*16,(w+1)*16); col-tiles ct(g) = g*8+w cover all 4 gates.
// C layout (16x16): col=lane&15 (gate-ch), row=(lane>>4)*4+reg (node). A: m=lane&15, k=quad*8+j.
__global__ __launch_bounds__(512) void lstm_l1f_kernel(
    const unsigned short* __restrict__ h0seq, // [N][12][128] bf16
    const unsigned short* __restrict__ Wpk,   // +65536 = Wih1(16), +131072 = Whh1(16)
    const float* __restrict__ bih1, const float* __restrict__ bhh1,
    float* __restrict__ hbuf,                 // [N][128] fp32 out
    int N, int ntiles)
{
    __shared__ unsigned short wlds[65536];    // Whh1, 128 KB
    __shared__ unsigned short hA1[64 * KS0];  // 17.4 KB

    const int tid  = threadIdx.x;
    const int w    = tid >> 6;                // 0..7: ch block
    const int ln   = tid & 63;
    const int l15  = ln & 15;
    const int quad = ln >> 4;
    const int ch   = w * 16 + l15;

    for (int i = tid * 8; i < 65536; i += 512 * 8)
        *(bf16x8*)(wlds + i) = *(const bf16x8*)(Wpk + 131072 + i);

    // Wih1 fragments -> registers (64 VGPR)
    bf16x8 wfr[4][4];
#pragma unroll
    for (int g = 0; g < 4; ++g)
#pragma unroll
        for (int ks = 0; ks < 4; ++ks) {
            int slot = (g * 8 + w) * 4 + ks;
            wfr[g][ks] = *(const bf16x8*)(Wpk + 65536 + ((size_t)(slot * 64 + ln) << 3));
        }

    float br1[4];
#pragma unroll
    for (int g = 0; g < 4; ++g) {
        int row = (g << 7) + ch;
        br1[g] = bih1[row] + bhh1[row];
    }

    const bf16x8 zv = {0, 0, 0, 0, 0, 0, 0, 0};
    __syncthreads();

    for (int tile = blockIdx.x; tile < ntiles; tile += gridDim.x) {
        __syncthreads();                       // prev tile hA1 reads done
        for (int i = tid; i < 64 * KS0; i += 512) hA1[i] = 0;
        float c1[16];
#pragma unroll
        for (int r = 0; r < 16; ++r) c1[r] = 0.f;
        __syncthreads();

        for (int t = 0; t < TT; ++t) {
            f32x4 acc[4][4];                   // [rt][g]
#pragma unroll
            for (int rt = 0; rt < 4; ++rt)
#pragma unroll
                for (int g = 0; g < 4; ++g)
#pragma unroll
                    for (int e = 0; e < 4; ++e) acc[rt][g][e] = 0.f;

            // input GEMM (global A, register B) — loads issue earliest
#pragma unroll
            for (int ks = 0; ks < 4; ++ks) {
                bf16x8 a[4];
#pragma unroll
                for (int rt = 0; rt < 4; ++rt) {
                    int n = tile * 64 + rt * 16 + l15;
                    a[rt] = (n < N)
                        ? __builtin_nontemporal_load(
                            (const bf16x8*)(h0seq + ((size_t)n * TT + t) * HDIM + ks * 32 + quad * 8))
                        : zv;
                }
#pragma unroll
                for (int g = 0; g < 4; ++g)
#pragma unroll
                    for (int rt = 0; rt < 4; ++rt)
                        acc[rt][g] = __builtin_amdgcn_mfma_f32_16x16x32_bf16(a[rt], wfr[g][ks], acc[rt][g], 0, 0, 0);
            }
            // recurrent GEMM (LDS A, LDS B)
#pragma unroll
            for (int ks = 0; ks < 4; ++ks) {
                bf16x8 a[4];
#pragma unroll
                for (int rt = 0; rt < 4; ++rt)
                    a[rt] = *(const bf16x8*)(hA1 + (rt * 16 + l15) * KS0 + ks * 32 + quad * 8);
#pragma unroll
                for (int g = 0; g < 4; ++g) {
                    int slot = (g * 8 + w) * 4 + ks;
                    bf16x8 b = *(const bf16x8*)(wlds + ((size_t)(slot * 64 + ln) << 3));
#pragma unroll
                    for (int rt = 0; rt < 4; ++rt)
                        acc[rt][g] = __builtin_amdgcn_mfma_f32_16x16x32_bf16(a[rt], b, acc[rt][g], 0, 0, 0);
                }
            }
            __syncthreads();                   // B1: hA1 reads done

#pragma unroll
            for (int rt = 0; rt < 4; ++rt) {
#pragma unroll
                for (int rg = 0; rg < 4; ++rg) {
                    int ci = rt * 4 + rg;
                    float zi = acc[rt][0][rg] + br1[0];
                    float zf = acc[rt][1][rg] + br1[1];
                    float zg = acc[rt][2][rg] + br1[2];
                    float zo = acc[rt][3][rg] + br1[3];
                    float cn = sigf(zf) * c1[ci] + sigf(zi) * tanh_fast(zg);
                    c1[ci] = cn;
                    float h = sigf(zo) * tanh_fast(cn);
                    int nd = rt * 16 + quad * 4 + rg;   // node within tile
                    if (t + 1 < TT) {
                        hA1[nd * KS0 + ch] = f2bf(h);
                    } else {
                        int n = tile * 64 + nd;
                        if (n < N) hbuf[n * HDIM + ch] = h;
                    }
                }
            }
            __syncthreads();                   // B2: h1_t visible
        }
    }
}

// ---------------- GCN: CSR build (unchanged) ----------------
__global__ void deg_count_kernel(const int* __restrict__ ei, int* __restrict__ degi, int E)
{
    int e = blockIdx.x * 256 + threadIdx.x;
    if (e < E) atomicAdd(&degi[ei[E + e]], 1);
}

__global__ void row_alloc_kernel(const int* __restrict__ degi, int* __restrict__ row_ptr,
                                 float* __restrict__ dinv, int* __restrict__ counter, int N)
{
    int n = blockIdx.x * 256 + threadIdx.x;
    int lane = threadIdx.x & 63;
    int v = (n < N) ? degi[n] : 0;
    int incl = v;
    for (int off = 1; off < 64; off <<= 1) {
        int u = __shfl_up(incl, off);
        if (lane >= off) incl += u;
    }
    int base = 0;
    if (lane == 63) base = atomicAdd(counter, incl);
    base = __shfl(base, 63);
    if (n < N) {
        row_ptr[n] = base + (incl - v);
        dinv[n] = rsqrtf((float)(v + 1));
    }
}

__global__ void csr_fill_kernel(const int* __restrict__ ei, const int* __restrict__ row_ptr,
                                int* __restrict__ fill, int* __restrict__ csr_src, int E)
{
    int e = blockIdx.x * 256 + threadIdx.x;
    if (e < E) {
        int d = ei[E + e];
        int p = atomicAdd(&fill[d], 1);
        csr_src[row_ptr[d] + p] = ei[e];
    }
}

// ---------------- GCN: transform + aggregate (fp16 messages) ----------------
__global__ __launch_bounds__(256) void gemm128_kernel(const float* __restrict__ X,
                                                      const float* __restrict__ W,
                                                      _Float16* __restrict__ Y, int N)
{
    __shared__ float XT[128 * TPAD];
    const int tid = threadIdx.x;
    const int nbase = blockIdx.x * 32;
    for (int idx = tid; idx < 32 * 128; idx += 256) {
        int m = idx >> 7, k = idx & 127;
        int n = nbase + m;
        XT[k * TPAD + m] = (n < N) ? X[n * HDIM + k] : 0.f;
    }
    __syncthreads();
    const int c  = tid & 63;
    const int mb = (tid >> 6) << 3;
    float acc[8][2];
#pragma unroll
    for (int i = 0; i < 8; ++i) { acc[i][0] = 0.f; acc[i][1] = 0.f; }
    for (int k = 0; k < 128; ++k) {
        const float* xr = &XT[k * TPAD + mb];
        float4 a0 = *(const float4*)(xr);
        float4 a1 = *(const float4*)(xr + 4);
        float a[8] = {a0.x, a0.y, a0.z, a0.w, a1.x, a1.y, a1.z, a1.w};
        float b0 = W[k * HDIM + c];
        float b1 = W[k * HDIM + c + 64];
#pragma unroll
        for (int i = 0; i < 8; ++i) {
            acc[i][0] = fmaf(a[i], b0, acc[i][0]);
            acc[i][1] = fmaf(a[i], b1, acc[i][1]);
        }
    }
#pragma unroll
    for (int i = 0; i < 8; ++i) {
        int n = nbase + mb + i;
        if (n < N) {
            Y[n * HDIM + c]      = (_Float16)acc[i][0];
            Y[n * HDIM + c + 64] = (_Float16)acc[i][1];
        }
    }
}

__global__ void gemm12_kernel(const float* __restrict__ X, const float* __restrict__ W2,
                              _Float16* __restrict__ Y, int N)
{
    int idx = blockIdx.x * 256 + threadIdx.x;
    int n = idx / ODIM, c = idx - n * ODIM;
    if (n >= N) return;
    float acc = 0.f;
    for (int k = 0; k < 128; ++k) acc = fmaf(X[n * HDIM + k], W2[k * ODIM + c], acc);
    Y[n * ODIM + c] = (_Float16)acc;
}

__global__ __launch_bounds__(128) void agg128_kernel(const _Float16* __restrict__ hW,
        const int* __restrict__ row_ptr, const int* __restrict__ degi,
        const int* __restrict__ csr_src, const float* __restrict__ dinv,
        const float* __restrict__ bias, float* __restrict__ out, int N, int do_relu)
{
    int n = blockIdx.x;
    int c = threadIdx.x;
    float dn = dinv[n];
    float acc = (float)hW[n * HDIM + c] * dn * dn;
    int start = row_ptr[n];
    int cnt = degi[n];
    for (int i = 0; i < cnt; ++i) {
        int s = csr_src[start + i];
        acc = fmaf((float)hW[s * HDIM + c], dinv[s] * dn, acc);
    }
    float v = acc + bias[c];
    if (do_relu) v = fmaxf(v, 0.f);
    out[n * HDIM + c] = v;
}

__global__ void agg12_kernel(const _Float16* __restrict__ hW, const int* __restrict__ row_ptr,
        const int* __restrict__ degi, const int* __restrict__ csr_src,
        const float* __restrict__ dinv, const float* __restrict__ b2,
        float* __restrict__ out, int N)
{
    int idx = blockIdx.x * 256 + threadIdx.x;
    int n = idx / ODIM, c = idx - n * ODIM;
    if (n >= N) return;
    float dn = dinv[n];
    float acc = (float)hW[n * ODIM + c] * dn * dn;
    int start = row_ptr[n], cnt = degi[n];
    for (int i = 0; i < cnt; ++i) {
        int s = csr_src[start + i];
        acc = fmaf((float)hW[s * ODIM + c], dinv[s] * dn, acc);
    }
    out[n * ODIM + c] = acc + b2[c];
}

extern "C" void kernel_launch(void* const* d_in, const int* in_sizes, int n_in,
                              void* d_out, int out_size, void* d_ws, size_t ws_size,
                              hipStream_t stream)
{
    const float* x     = (const float*)d_in[0];
    const int*   ei    = (const int*)d_in[1];
    const float* Wih0  = (const float*)d_in[2];
    const float* Whh0  = (const float*)d_in[3];
    const float* bih0  = (const float*)d_in[4];
    const float* bhh0  = (const float*)d_in[5];
    const float* Wih1  = (const float*)d_in[6];
    const float* Whh1  = (const float*)d_in[7];
    const float* bih1  = (const float*)d_in[8];
    const float* bhh1  = (const float*)d_in[9];
    const float* W0    = (const float*)d_in[10];
    const float* b0    = (const float*)d_in[11];
    const float* W1    = (const float*)d_in[12];
    const float* b1    = (const float*)d_in[13];
    const float* W2    = (const float*)d_in[14];
    const float* b2    = (const float*)d_in[15];
    float* out = (float*)d_out;

    const int N = in_sizes[0] / (TT * 2);
    const int E = in_sizes[1] / 2;

    // ---- workspace layout ----
    unsigned short* Wpk = (unsigned short*)d_ws;          // 384 KB
    float* fbase = (float*)((char*)d_ws + 393216);
    float* hbuf = fbase;                                  // N*128 fp32
    float* buf1 = hbuf + (size_t)N * HDIM;                // N*128 (fp16 messages live here)
    float* buf2 = buf1 + (size_t)N * HDIM;                // N*128 fp32
    float* dinv = buf2 + (size_t)N * HDIM;                // N
    int* degi    = (int*)(dinv + N);                      // N
    int* fill    = degi + N;                              // N
    int* counter = fill + N;                              // 1
    int* row_ptr = counter + 1;                           // N
    int* csr_src = row_ptr + N;                           // E
    size_t h0_off = (((size_t)((char*)(csr_src + E) - (char*)d_ws)) + 255) & ~(size_t)255;
    unsigned short* h0seq = (unsigned short*)((char*)d_ws + h0_off);   // N*12*128 bf16 (153.6 MB)
    _Float16* buf1h = (_Float16*)buf1;

    hipMemsetAsync(degi, 0, (size_t)(2 * N + 1) * sizeof(int), stream);

    pack_kernel<<<(384 * 64 + 255) / 256, 256, 0, stream>>>(Whh0, Wih1, Whh1, Wpk);

    const int ntiles = (N + 63) / 64;
    lstm_l0_kernel<<<256, 512, 0, stream>>>(x, Wpk, Wih0, bih0, bhh0, h0seq, N, ntiles);
    lstm_l1f_kernel<<<256, 512, 0, stream>>>(h0seq, Wpk, bih1, bhh1, hbuf, N, ntiles);

    deg_count_kernel<<<(E + 255) / 256, 256, 0, stream>>>(ei, degi, E);
    row_alloc_kernel<<<(N + 255) / 256, 256, 0, stream>>>(degi, row_ptr, dinv, counter, N);
    csr_fill_kernel<<<(E + 255) / 256, 256, 0, stream>>>(ei, row_ptr, fill, csr_src, E);

    gemm128_kernel<<<(N + 31) / 32, 256, 0, stream>>>(hbuf, W0, buf1h, N);
    agg128_kernel<<<N, 128, 0, stream>>>(buf1h, row_ptr, degi, csr_src, dinv, b0, buf2, N, 1);
    gemm128_kernel<<<(N + 31) / 32, 256, 0, stream>>>(buf2, W1, buf1h, N);
    agg128_kernel<<<N, 128, 0, stream>>>(buf1h, row_ptr, degi, csr_src, dinv, b1, buf2, N, 1);
    gemm12_kernel<<<((size_t)N * ODIM + 255) / 256, 256, 0, stream>>>(buf2, W2, buf1h, N);
    agg12_kernel<<<((size_t)N * ODIM + 255) / 256, 256, 0, stream>>>(
        buf1h, row_ptr, degi, csr_src, dinv, b2, out, N);
}